// Round 1
// baseline (708.834 us; speedup 1.0000x reference)
//
#include <hip/hip_runtime.h>
#include <hip/hip_bf16.h>
#include <math.h>

#define BATCH 4
#define NPTS 4096
#define DF 64
#define TILE 64
#define NT (NPTS / TILE)        // 64 tiles per side
#define INV_T 100.0f            // 1 / temperature
#define SCALE (1.0f / 16384.0f) // 1/(B*N) == 1/(B*M)

// One directional pass: for each (b, row i of X): sm = softmin-weighted avg over
// j of ||X[b,i]-Y[b,j]||; out += sm^3 * SCALE.
__global__ __launch_bounds__(256) void softmin_pass(const float* __restrict__ X,
                                                    const float* __restrict__ Y,
                                                    float* __restrict__ out) {
    __shared__ float xs[TILE][DF + 4];    // x tile, row-major, stride 68
    __shared__ float ysT[DF][TILE + 4];   // y tile transposed: ysT[k][c] = y[c][k]
    __shared__ float x2s[TILE];
    __shared__ float y2s[TILE];
    __shared__ float p2[16][TILE];        // squared-sum partials
    __shared__ float row_mn[TILE], row_s[TILE], row_t[TILE];

    const int tid = threadIdx.x;
    const int b  = blockIdx.y;
    const int nt = blockIdx.x;
    const int tx = tid & 15, ty = tid >> 4;
    const int r0 = ty * 4, c0 = tx * 4;

    const float* xbase = X + ((size_t)b * NPTS + (size_t)nt * TILE) * DF;
    const float* ybase = Y + (size_t)b * NPTS * DF;

    // ---- load x tile (a full-row tile is contiguous: TILE*DF floats) ----
    #pragma unroll
    for (int t = 0; t < 4; ++t) {
        int e = t * 256 + tid;            // float4 index 0..1023
        float4 f = ((const float4*)xbase)[e];
        int c = e >> 4;                   // tile row
        int k0 = (e & 15) << 2;           // feature offset
        xs[c][k0]   = f.x; xs[c][k0+1] = f.y;
        xs[c][k0+2] = f.z; xs[c][k0+3] = f.w;
        p2[e & 15][c] = f.x*f.x + f.y*f.y + f.z*f.z + f.w*f.w;
    }
    __syncthreads();
    if (tid < TILE) {
        float s = 0.f;
        #pragma unroll
        for (int q = 0; q < 16; ++q) s += p2[q][tid];
        x2s[tid] = s;
        row_mn[tid] = INFINITY; row_s[tid] = 0.f; row_t[tid] = 0.f;
    }
    __syncthreads();

    float x2r[4];
    #pragma unroll
    for (int i = 0; i < 4; ++i) x2r[i] = x2s[r0 + i];

    for (int mt = 0; mt < NT; ++mt) {
        __syncthreads();  // previous iteration's readers of ysT/y2s are done
        // ---- load y tile, store transposed ----
        const float* yt = ybase + (size_t)mt * TILE * DF;
        #pragma unroll
        for (int t = 0; t < 4; ++t) {
            int e = t * 256 + tid;
            float4 f = ((const float4*)yt)[e];
            int c = e >> 4;
            int k0 = (e & 15) << 2;
            ysT[k0][c]   = f.x; ysT[k0+1][c] = f.y;
            ysT[k0+2][c] = f.z; ysT[k0+3][c] = f.w;
            p2[e & 15][c] = f.x*f.x + f.y*f.y + f.z*f.z + f.w*f.w;
        }
        __syncthreads();
        if (tid < TILE) {
            float s = 0.f;
            #pragma unroll
            for (int q = 0; q < 16; ++q) s += p2[q][tid];
            y2s[tid] = s;
        }
        __syncthreads();

        // ---- 64x64 tile matmul: acc[i][j] = dot(x[r0+i], y[c0+j]) ----
        float acc[4][4] = {{0.f}};
        #pragma unroll 4
        for (int kk = 0; kk < 16; ++kk) {
            float a[4][4], bb[4][4];
            #pragma unroll
            for (int i = 0; i < 4; ++i) {
                float4 f = *(const float4*)&xs[r0 + i][kk * 4];
                a[i][0] = f.x; a[i][1] = f.y; a[i][2] = f.z; a[i][3] = f.w;
            }
            #pragma unroll
            for (int t = 0; t < 4; ++t) {
                float4 f = *(const float4*)&ysT[kk * 4 + t][c0];
                bb[t][0] = f.x; bb[t][1] = f.y; bb[t][2] = f.z; bb[t][3] = f.w;
            }
            #pragma unroll
            for (int i = 0; i < 4; ++i)
                #pragma unroll
                for (int j = 0; j < 4; ++j)
                    #pragma unroll
                    for (int t = 0; t < 4; ++t)
                        acc[i][j] = fmaf(a[i][t], bb[t][j], acc[i][j]);
        }

        // ---- epilogue: distances + per-row online softmin update ----
        float y2c[4];
        #pragma unroll
        for (int j = 0; j < 4; ++j) y2c[j] = y2s[c0 + j];

        #pragma unroll
        for (int i = 0; i < 4; ++i) {
            float d[4];
            float mnl = INFINITY;
            #pragma unroll
            for (int j = 0; j < 4; ++j) {
                float d2 = x2r[i] + y2c[j] - 2.0f * acc[i][j];
                d[j] = sqrtf(fmaxf(d2, 0.0f));
                mnl = fminf(mnl, d[j]);
            }
            #pragma unroll
            for (int m = 1; m < 16; m <<= 1)
                mnl = fminf(mnl, __shfl_xor(mnl, m, 16));
            float s = 0.f, t = 0.f;
            #pragma unroll
            for (int j = 0; j < 4; ++j) {
                float e = __expf(INV_T * (mnl - d[j]));  // exp(-(d-min)/T) <= 1
                s += e;
                t += e * d[j];
            }
            #pragma unroll
            for (int m = 1; m < 16; m <<= 1) {
                s += __shfl_xor(s, m, 16);
                t += __shfl_xor(t, m, 16);
            }
            if (tx == 0) {
                int r = r0 + i;
                float omn = row_mn[r];
                float nmn = fminf(omn, mnl);
                float co = __expf(INV_T * (nmn - omn));  // 0 when omn == INF
                float ct = __expf(INV_T * (nmn - mnl));
                row_mn[r] = nmn;
                row_s[r] = row_s[r] * co + s * ct;
                row_t[r] = row_t[r] * co + t * ct;
            }
        }
    }

    __syncthreads();
    if (tid < TILE) {
        float sm = row_t[tid] / row_s[tid];
        float v = sm * sm * sm * SCALE;
        #pragma unroll
        for (int m = 1; m < 64; m <<= 1) v += __shfl_xor(v, m, 64);
        if (tid == 0) atomicAdd(out, v);
    }
}

__global__ void zero_kernel(float* out) {
    if (threadIdx.x == 0) out[0] = 0.0f;
}

extern "C" void kernel_launch(void* const* d_in, const int* in_sizes, int n_in,
                              void* d_out, int out_size, void* d_ws, size_t ws_size,
                              hipStream_t stream) {
    const float* x = (const float*)d_in[0];
    const float* y = (const float*)d_in[1];
    float* out = (float*)d_out;

    zero_kernel<<<1, 64, 0, stream>>>(out);
    dim3 grid(NT, BATCH);
    // precision term: softmin over targets for each prediction row
    softmin_pass<<<grid, 256, 0, stream>>>(x, y, out);
    // coverage term: softmin over predictions for each target row (x<->y swap)
    softmin_pass<<<grid, 256, 0, stream>>>(y, x, out);
}

// Round 2
// 134.196 us; speedup vs baseline: 5.2821x; 5.2821x over previous
//
#include <hip/hip_runtime.h>
#include <math.h>

#define BATCH 4
#define NPTS 4096
#define DF 64
#define ROWB 128               // bytes per point row in bf16
#define TILE 64                // col tile per iter
#define MC 4                   // M split into 4 chunks (parallelism)
#define CHUNK (NPTS / MC)      // 1024
#define ITERS (CHUNK / TILE)   // 16
#define INV_T 100.0f
#define MARGIN 0.16f           // skip weight bound exp(-16) ~ 1.1e-7
#define SCALE (1.0f / 16384.0f)

typedef float  f32x4 __attribute__((ext_vector_type(4)));
typedef short  s16x8 __attribute__((ext_vector_type(8)));
typedef unsigned short u16;

// ws layout (bytes); requires ~6.2 MB
#define SZ_B   (BATCH * NPTS * DF * 2)   // one bf16 array: 2 MB
#define SZ_N   (BATCH * NPTS * 4)        // one norm array: 64 KB
#define OFF_XB 0
#define OFF_YB (OFF_XB + SZ_B)
#define OFF_X2 (OFF_YB + SZ_B)
#define OFF_Y2 (OFF_X2 + SZ_N)
#define OFF_PART (OFF_Y2 + SZ_N)         // [dir*4+b][MC][NPTS][4] floats: 2 MB

__device__ __forceinline__ u16 f2bf(float f) {
    unsigned u = __float_as_uint(f);
    unsigned r = (u + 0x7fffu + ((u >> 16) & 1u)) >> 16;   // RNE
    return (u16)r;
}

// fp32 -> bf16 (linear layout) + fp32 norms. blockIdx.y: 0=x, 1=y.
__global__ __launch_bounds__(256) void prep_kernel(const float* __restrict__ X,
                                                   const float* __restrict__ Y,
                                                   u16* __restrict__ xb, u16* __restrict__ yb,
                                                   float* __restrict__ x2, float* __restrict__ y2) {
    const float* src = blockIdx.y ? Y : X;
    u16* dstb   = blockIdx.y ? yb : xb;
    float* dstn = blockIdx.y ? y2 : x2;
    int g = blockIdx.x * 256 + threadIdx.x;   // 0 .. 262143
    int p = g >> 4;                            // point 0..16383
    int sub = g & 15;                          // float4 chunk within point
    float4 v = ((const float4*)src)[(size_t)p * 16 + sub];
    float n4 = v.x * v.x + v.y * v.y + v.z * v.z + v.w * v.w;
    #pragma unroll
    for (int m = 1; m < 16; m <<= 1) n4 += __shfl_xor(n4, m, 16);
    ushort4 h;
    h.x = f2bf(v.x); h.y = f2bf(v.y); h.z = f2bf(v.z); h.w = f2bf(v.w);
    ((ushort4*)dstb)[(size_t)p * 16 + sub] = h;
    if (sub == 0) dstn[p] = n4;
}

// One (row-tile, col-chunk, batch, dir) partial softmin pass.
__global__ __launch_bounds__(256, 4) void softmin_main(const u16* __restrict__ xb,
                                                       const u16* __restrict__ yb,
                                                       const float* __restrict__ x2g,
                                                       const float* __restrict__ y2g,
                                                       float* __restrict__ part) {
    __shared__ u16 xs[TILE * DF];   // 8 KB, XOR-swizzled rows
    __shared__ u16 ys[TILE * DF];   // 8 KB, XOR-swizzled rows
    __shared__ float y2s[TILE];

    const int tid = threadIdx.x;
    const int nt  = blockIdx.x;          // row tile
    const int b   = blockIdx.y & 3;
    const int mc  = blockIdx.y >> 2;
    const int dir = blockIdx.z;

    const u16 *rowsrc, *colsrc; const float *rn, *cn;
    if (dir == 0) { rowsrc = xb; colsrc = yb; rn = x2g; cn = y2g; }
    else          { rowsrc = yb; colsrc = xb; rn = y2g; cn = x2g; }

    const int wr = tid >> 6;             // wave 0..3 -> 16-row strip
    const int h  = (tid >> 4) & 3;       // k-octet / D-row group
    const int c  = tid & 15;             // col slot / A-row

    const size_t bpts = (size_t)b * NPTS;
    const int row0 = nt * TILE;
    const u16* rbase = rowsrc + (bpts + row0) * DF;
    const u16* cbase = colsrc + (bpts + (size_t)mc * CHUNK) * DF;
    const float* cnb = cn + bpts + (size_t)mc * CHUNK;

    // ---- stage row tile (swizzled: byte ^= (row&7)<<4) ----
    #pragma unroll
    for (int q = 0; q < 2; ++q) {
        int e = q * 256 + tid;           // 16B chunk id 0..511
        int p = e >> 3;
        int o = (e & 7) << 4;
        s16x8 v = *(const s16x8*)((const char*)rbase + p * ROWB + o);
        *(s16x8*)((char*)xs + p * ROWB + (o ^ ((p & 7) << 4))) = v;
    }
    // row norms for this lane's 4 output rows (D rows = wr*16 + 4h + r)
    float x2r[4];
    #pragma unroll
    for (int r = 0; r < 4; ++r)
        x2r[r] = rn[bpts + row0 + wr * 16 + 4 * h + r];
    __syncthreads();

    // ---- A fragments in registers (A row = wr*16 + c, k-octet = h) ----
    s16x8 afrag[2];
    {
        int r = wr * 16 + c;
        #pragma unroll
        for (int kp = 0; kp < 2; ++kp) {
            int o = (h * 16 + kp * 64) ^ ((r & 7) << 4);
            afrag[kp] = *(const s16x8*)((const char*)xs + r * ROWB + o);
        }
    }

    float mn[4], ss[4], tt[4], thr2[4];
    #pragma unroll
    for (int r = 0; r < 4; ++r) { mn[r] = INFINITY; ss[r] = 0.f; tt[r] = 0.f; thr2[r] = INFINITY; }

    for (int it = 0; it < ITERS; ++it) {
        __syncthreads();
        const u16* csrc = cbase + (size_t)it * TILE * DF;
        #pragma unroll
        for (int q = 0; q < 2; ++q) {
            int e = q * 256 + tid;
            int p = e >> 3;
            int o = (e & 7) << 4;
            s16x8 v = *(const s16x8*)((const char*)csrc + p * ROWB + o);
            *(s16x8*)((char*)ys + p * ROWB + (o ^ ((p & 7) << 4))) = v;
        }
        if (tid < TILE) y2s[tid] = cnb[it * TILE + tid];
        __syncthreads();

        #pragma unroll
        for (int ct = 0; ct < 4; ++ct) {
            int pt = ct * 16 + c;
            f32x4 acc = {0.f, 0.f, 0.f, 0.f};
            #pragma unroll
            for (int kp = 0; kp < 2; ++kp) {
                int o = (h * 16 + kp * 64) ^ ((pt & 7) << 4);
                s16x8 bfrag = *(const s16x8*)((const char*)ys + pt * ROWB + o);
                acc = __builtin_amdgcn_mfma_f32_16x16x32_bf16(afrag[kp], bfrag, acc, 0, 0, 0);
            }
            float y2c = y2s[ct * 16 + c];
            #pragma unroll
            for (int r = 0; r < 4; ++r) {
                float d2 = fmaf(-2.f, acc[r], x2r[r] + y2c);
                if (d2 < thr2[r]) {                       // rare: within 0.16 of running min
                    float d = sqrtf(fmaxf(d2, 0.f));
                    if (d < mn[r]) {                      // rarer: new running min -> rescale
                        float co = __expf(INV_T * (d - mn[r]));  // exp(-inf)=0 on first hit
                        ss[r] *= co; tt[r] *= co;
                        mn[r] = d;
                        thr2[r] = (d + MARGIN) * (d + MARGIN);
                    }
                    float e = __expf(INV_T * (mn[r] - d));
                    ss[r] += e;
                    tt[r] = fmaf(e, d, tt[r]);
                }
            }
        }
    }

    // ---- merge states across the 16 lanes sharing (wr, h) ----
    #pragma unroll
    for (int r = 0; r < 4; ++r) {
        #pragma unroll
        for (int m = 1; m < 16; m <<= 1) {
            float om = __shfl_xor(mn[r], m, 16);
            float os = __shfl_xor(ss[r], m, 16);
            float ot = __shfl_xor(tt[r], m, 16);
            float nm = fminf(mn[r], om);
            float c0 = __expf(INV_T * (nm - mn[r]));
            float c1 = __expf(INV_T * (nm - om));
            ss[r] = ss[r] * c0 + os * c1;
            tt[r] = tt[r] * c0 + ot * c1;
            mn[r] = nm;
        }
    }
    if (c == 0) {
        int dirb = dir * 4 + b;
        #pragma unroll
        for (int r = 0; r < 4; ++r) {
            int row = row0 + wr * 16 + 4 * h + r;
            float* pp = part + (((size_t)(dirb * MC + mc)) * NPTS + row) * 4;
            pp[0] = mn[r]; pp[1] = ss[r]; pp[2] = tt[r];
        }
    }
}

// Merge MC partial states per row, cube, reduce, atomicAdd into out[0].
__global__ __launch_bounds__(256) void merge_kernel(const float* __restrict__ part,
                                                    float* __restrict__ out) {
    __shared__ float red[4];
    int g = blockIdx.x * 256 + threadIdx.x;   // 0..32767 = (dir*4+b)*4096 + row
    int dirb = g >> 12;
    int row  = g & 4095;
    const float* p0 = part + (((size_t)dirb * MC) * NPTS + row) * 4;
    float mnv[MC], sv[MC], tv[MC];
    float nm = INFINITY;
    #pragma unroll
    for (int k = 0; k < MC; ++k) {
        const float* p = p0 + (size_t)k * NPTS * 4;
        mnv[k] = p[0]; sv[k] = p[1]; tv[k] = p[2];
        nm = fminf(nm, mnv[k]);
    }
    float S = 0.f, T = 0.f;
    #pragma unroll
    for (int k = 0; k < MC; ++k) {
        float cw = __expf(INV_T * (nm - mnv[k]));
        S += sv[k] * cw;
        T += tv[k] * cw;
    }
    float sm = T / S;
    float v = sm * sm * sm * SCALE;
    #pragma unroll
    for (int m = 1; m < 64; m <<= 1) v += __shfl_xor(v, m, 64);
    if ((threadIdx.x & 63) == 0) red[threadIdx.x >> 6] = v;
    __syncthreads();
    if (threadIdx.x == 0) atomicAdd(out, red[0] + red[1] + red[2] + red[3]);
}

__global__ void zero_kernel(float* out) {
    if (threadIdx.x == 0) out[0] = 0.0f;
}

extern "C" void kernel_launch(void* const* d_in, const int* in_sizes, int n_in,
                              void* d_out, int out_size, void* d_ws, size_t ws_size,
                              hipStream_t stream) {
    const float* x = (const float*)d_in[0];
    const float* y = (const float*)d_in[1];
    float* out = (float*)d_out;
    char* ws = (char*)d_ws;

    u16* xb = (u16*)(ws + OFF_XB);
    u16* yb = (u16*)(ws + OFF_YB);
    float* x2 = (float*)(ws + OFF_X2);
    float* y2 = (float*)(ws + OFF_Y2);
    float* part = (float*)(ws + OFF_PART);

    zero_kernel<<<1, 64, 0, stream>>>(out);
    prep_kernel<<<dim3(1024, 2), 256, 0, stream>>>(x, y, xb, yb, x2, y2);
    softmin_main<<<dim3(NPTS / TILE, 4 * MC, 2), 256, 0, stream>>>(xb, yb, x2, y2, part);
    merge_kernel<<<128, 256, 0, stream>>>(part, out);
}

// Round 3
// 116.868 us; speedup vs baseline: 6.0652x; 1.1483x over previous
//
#include <hip/hip_runtime.h>
#include <math.h>

#define BATCH 4
#define NPTS 4096
#define DF 64
#define ROWB 128               // bytes per point row in bf16
#define TILE 64                // col tile per iter
#define NT (NPTS / TILE)       // 64 tiles
#define INV_T 100.0f
#define MARGIN 0.16f           // skipped weights < exp(-16) ~ 1.1e-7
#define SCALE (1.0f / 16384.0f)

typedef float  f32x4 __attribute__((ext_vector_type(4)));
typedef short  s16x8 __attribute__((ext_vector_type(8)));
typedef unsigned short u16;

// ws layout
#define SZ_B   (BATCH * NPTS * DF * 2)   // one bf16 array: 2 MB
#define SZ_N   (BATCH * NPTS * 4)        // one norm array: 64 KB
#define OFF_XB 0
#define OFF_YB (OFF_XB + SZ_B)
#define OFF_X2 (OFF_YB + SZ_B)
#define OFF_Y2 (OFF_X2 + SZ_N)

__device__ __forceinline__ u16 f2bf(float f) {
    unsigned u = __float_as_uint(f);
    unsigned r = (u + 0x7fffu + ((u >> 16) & 1u)) >> 16;   // RNE
    return (u16)r;
}

// fp32 -> bf16 + fp32 norms. blockIdx.y: 0=x, 1=y.
__global__ __launch_bounds__(256) void prep_kernel(const float* __restrict__ X,
                                                   const float* __restrict__ Y,
                                                   u16* __restrict__ xb, u16* __restrict__ yb,
                                                   float* __restrict__ x2, float* __restrict__ y2) {
    const float* src = blockIdx.y ? Y : X;
    u16* dstb   = blockIdx.y ? yb : xb;
    float* dstn = blockIdx.y ? y2 : x2;
    int g = blockIdx.x * 256 + threadIdx.x;
    int p = g >> 4;
    int sub = g & 15;
    float4 v = ((const float4*)src)[(size_t)p * 16 + sub];
    float n4 = v.x * v.x + v.y * v.y + v.z * v.z + v.w * v.w;
    #pragma unroll
    for (int m = 1; m < 16; m <<= 1) n4 += __shfl_xor(n4, m, 16);
    ushort4 h;
    h.x = f2bf(v.x); h.y = f2bf(v.y); h.z = f2bf(v.z); h.w = f2bf(v.w);
    ((ushort4*)dstb)[(size_t)p * 16 + sub] = h;
    if (sub == 0) dstn[p] = n4;
}

// Fused two-phase softmin: block = 64 rows x ALL 4096 cols of one (b, dir).
// Loop 1: exact row-min of d^2 (branchless). Loop 2: gated weighted sum.
__global__ __launch_bounds__(256) void softmin_fused(const u16* __restrict__ xb,
                                                     const u16* __restrict__ yb,
                                                     const float* __restrict__ x2g,
                                                     const float* __restrict__ y2g,
                                                     float* __restrict__ out) {
    __shared__ u16 xs[TILE * DF];
    __shared__ u16 ys[TILE * DF];
    __shared__ float y2s[TILE];
    __shared__ float blkred[16];

    const int tid = threadIdx.x;
    const int nt  = blockIdx.x;
    const int b   = blockIdx.y;
    const int dir = blockIdx.z;

    const u16 *rowsrc, *colsrc; const float *rn, *cn;
    if (dir == 0) { rowsrc = xb; colsrc = yb; rn = x2g; cn = y2g; }
    else          { rowsrc = yb; colsrc = xb; rn = y2g; cn = x2g; }

    const int wr = tid >> 6;             // wave -> 16-row strip
    const int h  = (tid >> 4) & 3;       // k-octet / D-row group
    const int c  = tid & 15;             // col slot / A-row

    const size_t bpts = (size_t)b * NPTS;
    const int row0 = nt * TILE;
    const u16* rbase = rowsrc + (bpts + row0) * DF;
    const u16* cbase = colsrc + bpts * DF;
    const float* cnb = cn + bpts;

    // ---- stage row tile (swizzle: byte ^= (point&7)<<4) ----
    #pragma unroll
    for (int q = 0; q < 2; ++q) {
        int e = q * 256 + tid;
        int p = e >> 3;
        int o = (e & 7) << 4;
        s16x8 v = *(const s16x8*)((const char*)rbase + p * ROWB + o);
        *(s16x8*)((char*)xs + p * ROWB + (o ^ ((p & 7) << 4))) = v;
    }
    float x2r[4];
    #pragma unroll
    for (int r = 0; r < 4; ++r)
        x2r[r] = rn[bpts + row0 + wr * 16 + 4 * h + r];
    __syncthreads();

    s16x8 afrag[2];
    {
        int r = wr * 16 + c;
        #pragma unroll
        for (int kp = 0; kp < 2; ++kp) {
            int o = (h * 16 + kp * 64) ^ ((r & 7) << 4);
            afrag[kp] = *(const s16x8*)((const char*)xs + r * ROWB + o);
        }
    }

    // per-thread staging slots (two 16B chunks per tile)
    const int sp  = tid >> 3;            // point 0..31 (chunk0); chunk1 = sp+32
    const int so  = (tid & 7) << 4;      // byte offset in row
    const int swz = so ^ ((sp & 7) << 4);   // (sp+32)&7 == sp&7

    float rmin[4];
    #pragma unroll
    for (int r = 0; r < 4; ++r) rmin[r] = INFINITY;

    // ================= LOOP 1: exact row min of d^2 =================
    s16x8 v0 = *(const s16x8*)((const char*)cbase + sp * ROWB + so);
    s16x8 v1 = *(const s16x8*)((const char*)cbase + (sp + 32) * ROWB + so);
    float yr = (tid < TILE) ? cnb[tid] : 0.f;

    for (int it = 0; it < NT; ++it) {
        __syncthreads();
        *(s16x8*)((char*)ys + sp * ROWB + swz) = v0;
        *(s16x8*)((char*)ys + (sp + 32) * ROWB + swz) = v1;
        if (tid < TILE) y2s[tid] = yr;
        if (it + 1 < NT) {
            const char* nsrc = (const char*)(cbase + (size_t)(it + 1) * TILE * DF);
            v0 = *(const s16x8*)(nsrc + sp * ROWB + so);
            v1 = *(const s16x8*)(nsrc + (sp + 32) * ROWB + so);
            yr = (tid < TILE) ? cnb[(it + 1) * TILE + tid] : 0.f;
        }
        __syncthreads();

        #pragma unroll
        for (int ct = 0; ct < 4; ++ct) {
            int pt = ct * 16 + c;
            f32x4 acc = {0.f, 0.f, 0.f, 0.f};
            #pragma unroll
            for (int kp = 0; kp < 2; ++kp) {
                int o = (h * 16 + kp * 64) ^ ((pt & 7) << 4);
                s16x8 bfrag = *(const s16x8*)((const char*)ys + pt * ROWB + o);
                acc = __builtin_amdgcn_mfma_f32_16x16x32_bf16(afrag[kp], bfrag, acc, 0, 0, 0);
            }
            float y2c = y2s[pt];
            #pragma unroll
            for (int r = 0; r < 4; ++r) {
                float d2 = fmaf(-2.f, acc[r], x2r[r] + y2c);
                rmin[r] = fminf(rmin[r], d2);
            }
        }
    }

    // merge min across the 16 col-lanes (same 4 rows)
    #pragma unroll
    for (int r = 0; r < 4; ++r) {
        #pragma unroll
        for (int m = 1; m < 16; m <<= 1)
            rmin[r] = fminf(rmin[r], __shfl_xor(rmin[r], m, 16));
    }
    float mval[4], thr2[4], ssum[4], tsum[4];
    #pragma unroll
    for (int r = 0; r < 4; ++r) {
        mval[r] = sqrtf(fmaxf(rmin[r], 0.f));
        float th = mval[r] + MARGIN;
        thr2[r] = th * th;
        ssum[r] = 0.f; tsum[r] = 0.f;
    }

    // ================= LOOP 2: gated weighted sums =================
    v0 = *(const s16x8*)((const char*)cbase + sp * ROWB + so);
    v1 = *(const s16x8*)((const char*)cbase + (sp + 32) * ROWB + so);
    yr = (tid < TILE) ? cnb[tid] : 0.f;

    for (int it = 0; it < NT; ++it) {
        __syncthreads();
        *(s16x8*)((char*)ys + sp * ROWB + swz) = v0;
        *(s16x8*)((char*)ys + (sp + 32) * ROWB + swz) = v1;
        if (tid < TILE) y2s[tid] = yr;
        if (it + 1 < NT) {
            const char* nsrc = (const char*)(cbase + (size_t)(it + 1) * TILE * DF);
            v0 = *(const s16x8*)(nsrc + sp * ROWB + so);
            v1 = *(const s16x8*)(nsrc + (sp + 32) * ROWB + so);
            yr = (tid < TILE) ? cnb[(it + 1) * TILE + tid] : 0.f;
        }
        __syncthreads();

        #pragma unroll
        for (int ct = 0; ct < 4; ++ct) {
            int pt = ct * 16 + c;
            f32x4 acc = {0.f, 0.f, 0.f, 0.f};
            #pragma unroll
            for (int kp = 0; kp < 2; ++kp) {
                int o = (h * 16 + kp * 64) ^ ((pt & 7) << 4);
                s16x8 bfrag = *(const s16x8*)((const char*)ys + pt * ROWB + o);
                acc = __builtin_amdgcn_mfma_f32_16x16x32_bf16(afrag[kp], bfrag, acc, 0, 0, 0);
            }
            float y2c = y2s[pt];
            float d2v[4];
            int q = 0;
            #pragma unroll
            for (int r = 0; r < 4; ++r) {
                d2v[r] = fmaf(-2.f, acc[r], x2r[r] + y2c);   // identical to loop 1
                q |= (d2v[r] < thr2[r]) ? 1 : 0;
            }
            if (q) {   // ~12% of wave-iterations
                #pragma unroll
                for (int r = 0; r < 4; ++r) {
                    float d = sqrtf(fmaxf(d2v[r], 0.f));
                    float e = __expf(INV_T * (mval[r] - d));  // underflows to 0 if far
                    ssum[r] += e;
                    tsum[r] = fmaf(e, d, tsum[r]);
                }
            }
        }
    }

    // reduce sums across the 16 col-lanes
    #pragma unroll
    for (int r = 0; r < 4; ++r) {
        #pragma unroll
        for (int m = 1; m < 16; m <<= 1) {
            ssum[r] += __shfl_xor(ssum[r], m, 16);
            tsum[r] += __shfl_xor(tsum[r], m, 16);
        }
    }
    float v = 0.f;
    if (c == 0) {
        #pragma unroll
        for (int r = 0; r < 4; ++r) {
            float sm = tsum[r] / ssum[r];
            v += sm * sm * sm;
        }
        blkred[wr * 4 + h] = v;
    }
    __syncthreads();
    if (tid == 0) {
        float s = 0.f;
        #pragma unroll
        for (int i = 0; i < 16; ++i) s += blkred[i];
        atomicAdd(out, s * SCALE);
    }
}

__global__ void zero_kernel(float* out) {
    if (threadIdx.x == 0) out[0] = 0.0f;
}

extern "C" void kernel_launch(void* const* d_in, const int* in_sizes, int n_in,
                              void* d_out, int out_size, void* d_ws, size_t ws_size,
                              hipStream_t stream) {
    const float* x = (const float*)d_in[0];
    const float* y = (const float*)d_in[1];
    float* out = (float*)d_out;
    char* ws = (char*)d_ws;

    u16* xb = (u16*)(ws + OFF_XB);
    u16* yb = (u16*)(ws + OFF_YB);
    float* x2 = (float*)(ws + OFF_X2);
    float* y2 = (float*)(ws + OFF_Y2);

    zero_kernel<<<1, 64, 0, stream>>>(out);
    prep_kernel<<<dim3(1024, 2), 256, 0, stream>>>(x, y, xb, yb, x2, y2);
    softmin_fused<<<dim3(NT, BATCH, 2), 256, 0, stream>>>(xb, yb, x2, y2, out);
}

// Round 4
// 87.928 us; speedup vs baseline: 8.0615x; 1.3291x over previous
//
#include <hip/hip_runtime.h>
#include <math.h>

#define BATCH 4
#define NPTS 4096
#define DF 64
#define ROWB 128               // bytes per point row in bf16
#define TILE 64                // col tile per iter
#define MC 4                   // col splits for occupancy
#define CHUNK (NPTS / MC)      // 1024
#define ITERS (CHUNK / TILE)   // 16
#define INV_T 100.0f
#define MARGIN 0.16f           // skipped weights < exp(-16) ~ 1.1e-7
#define SCALE (1.0f / 16384.0f)

typedef float  f32x4 __attribute__((ext_vector_type(4)));
typedef short  s16x8 __attribute__((ext_vector_type(8)));
typedef unsigned short u16;

// ws layout (max 6.19 MB -- proven to fit in R2)
#define SZ_B   (BATCH * NPTS * DF * 2)   // bf16 array: 2 MB
#define SZ_N   (BATCH * NPTS * 4)        // norm array: 64 KB
#define OFF_XB 0
#define OFF_YB (OFF_XB + SZ_B)
#define OFF_X2 (OFF_YB + SZ_B)
#define OFF_Y2 (OFF_X2 + SZ_N)
#define OFF_PART (OFF_Y2 + SZ_N)         // [dir*4+b][MC][NPTS][4] floats: 2 MB

__device__ __forceinline__ u16 f2bf(float f) {
    unsigned u = __float_as_uint(f);
    unsigned r = (u + 0x7fffu + ((u >> 16) & 1u)) >> 16;   // RNE
    return (u16)r;
}

__global__ __launch_bounds__(256) void prep_kernel(const float* __restrict__ X,
                                                   const float* __restrict__ Y,
                                                   u16* __restrict__ xb, u16* __restrict__ yb,
                                                   float* __restrict__ x2, float* __restrict__ y2) {
    const float* src = blockIdx.y ? Y : X;
    u16* dstb   = blockIdx.y ? yb : xb;
    float* dstn = blockIdx.y ? y2 : x2;
    int g = blockIdx.x * 256 + threadIdx.x;
    int p = g >> 4;
    int sub = g & 15;
    float4 v = ((const float4*)src)[(size_t)p * 16 + sub];
    float n4 = v.x * v.x + v.y * v.y + v.z * v.z + v.w * v.w;
    #pragma unroll
    for (int m = 1; m < 16; m <<= 1) n4 += __shfl_xor(n4, m, 16);
    ushort4 h;
    h.x = f2bf(v.x); h.y = f2bf(v.y); h.z = f2bf(v.z); h.w = f2bf(v.w);
    ((ushort4*)dstb)[(size_t)p * 16 + sub] = h;
    if (sub == 0) dstn[p] = n4;
}

// Two-phase partial softmin: block = 64 rows x 1024 cols of one (b, dir).
// Loop 1: exact patch-min via max(acc - y2/2). Loop 2: gated weighted sums.
__global__ __launch_bounds__(256, 8) void softmin_fused(const u16* __restrict__ xb,
                                                        const u16* __restrict__ yb,
                                                        const float* __restrict__ x2g,
                                                        const float* __restrict__ y2g,
                                                        float* __restrict__ part) {
    __shared__ u16 xs[TILE * DF];
    __shared__ u16 ys[TILE * DF];
    __shared__ float y2s[TILE];

    const int tid = threadIdx.x;
    const int nt  = blockIdx.x;
    const int b   = blockIdx.y & 3;
    const int cs  = blockIdx.y >> 2;
    const int dir = blockIdx.z;

    const u16 *rowsrc, *colsrc; const float *rn, *cn;
    if (dir == 0) { rowsrc = xb; colsrc = yb; rn = x2g; cn = y2g; }
    else          { rowsrc = yb; colsrc = xb; rn = y2g; cn = x2g; }

    const int wr = tid >> 6;             // wave -> 16-row strip
    const int h  = (tid >> 4) & 3;       // k-octet / D-row group
    const int c  = tid & 15;             // col slot / A-row

    const size_t bpts = (size_t)b * NPTS;
    const int row0 = nt * TILE;
    const u16* rbase = rowsrc + (bpts + row0) * DF;
    const u16* cbase = colsrc + (bpts + (size_t)cs * CHUNK) * DF;
    const float* cnb = cn + bpts + (size_t)cs * CHUNK;

    // ---- stage row tile (swizzle: byte ^= (point&7)<<4) ----
    #pragma unroll
    for (int q = 0; q < 2; ++q) {
        int e = q * 256 + tid;
        int p = e >> 3;
        int o = (e & 7) << 4;
        s16x8 v = *(const s16x8*)((const char*)rbase + p * ROWB + o);
        *(s16x8*)((char*)xs + p * ROWB + (o ^ ((p & 7) << 4))) = v;
    }
    float x2r[4];
    #pragma unroll
    for (int r = 0; r < 4; ++r)
        x2r[r] = rn[bpts + row0 + wr * 16 + 4 * h + r];
    __syncthreads();

    s16x8 afrag[2];
    {
        int r = wr * 16 + c;
        #pragma unroll
        for (int kp = 0; kp < 2; ++kp) {
            int o = (h * 16 + kp * 64) ^ ((r & 7) << 4);
            afrag[kp] = *(const s16x8*)((const char*)xs + r * ROWB + o);
        }
    }

    // per-thread staging slots (two 16B chunks per tile)
    const int sp  = tid >> 3;            // point 0..31 (chunk0); chunk1 = sp+32
    const int so  = (tid & 7) << 4;      // byte offset in row
    const int swz = so ^ ((sp & 7) << 4);   // (sp+32)&7 == sp&7

    float mx[4];
    #pragma unroll
    for (int r = 0; r < 4; ++r) mx[r] = -INFINITY;

    // ================= LOOP 1: exact row max of (acc - y2/2) =================
    s16x8 v0 = *(const s16x8*)((const char*)cbase + sp * ROWB + so);
    s16x8 v1 = *(const s16x8*)((const char*)cbase + (sp + 32) * ROWB + so);
    float yr = (tid < TILE) ? cnb[tid] : 0.f;

    for (int it = 0; it < ITERS; ++it) {
        __syncthreads();
        *(s16x8*)((char*)ys + sp * ROWB + swz) = v0;
        *(s16x8*)((char*)ys + (sp + 32) * ROWB + swz) = v1;
        if (tid < TILE) y2s[tid] = yr;
        if (it + 1 < ITERS) {
            const char* nsrc = (const char*)(cbase + (size_t)(it + 1) * TILE * DF);
            v0 = *(const s16x8*)(nsrc + sp * ROWB + so);
            v1 = *(const s16x8*)(nsrc + (sp + 32) * ROWB + so);
            yr = (tid < TILE) ? cnb[(it + 1) * TILE + tid] : 0.f;
        }
        __syncthreads();

        #pragma unroll
        for (int ct = 0; ct < 4; ++ct) {
            int pt = ct * 16 + c;
            f32x4 acc = {0.f, 0.f, 0.f, 0.f};
            #pragma unroll
            for (int kp = 0; kp < 2; ++kp) {
                int o = (h * 16 + kp * 64) ^ ((pt & 7) << 4);
                s16x8 bfrag = *(const s16x8*)((const char*)ys + pt * ROWB + o);
                acc = __builtin_amdgcn_mfma_f32_16x16x32_bf16(afrag[kp], bfrag, acc, 0, 0, 0);
            }
            float y2c = y2s[pt];
            #pragma unroll
            for (int r = 0; r < 4; ++r)
                mx[r] = fmaxf(mx[r], fmaf(-0.5f, y2c, acc[r]));
        }
    }

    // merge max across the 16 col-lanes; derive min distance + gate threshold
    float mval[4], gthr[4], ssum[4], tsum[4];
    #pragma unroll
    for (int r = 0; r < 4; ++r) {
        #pragma unroll
        for (int m = 1; m < 16; m <<= 1)
            mx[r] = fmaxf(mx[r], __shfl_xor(mx[r], m, 16));
        float rmin = fmaf(-2.f, mx[r], x2r[r]);          // exact min d^2
        mval[r] = sqrtf(fmaxf(rmin, 0.f));
        float th = mval[r] + MARGIN;
        gthr[r] = 0.5f * (x2r[r] - th * th);             // u > gthr <=> d2 < th^2
        ssum[r] = 0.f; tsum[r] = 0.f;
    }

    // ================= LOOP 2: gated weighted sums =================
    v0 = *(const s16x8*)((const char*)cbase + sp * ROWB + so);
    v1 = *(const s16x8*)((const char*)cbase + (sp + 32) * ROWB + so);
    yr = (tid < TILE) ? cnb[tid] : 0.f;

    for (int it = 0; it < ITERS; ++it) {
        __syncthreads();
        *(s16x8*)((char*)ys + sp * ROWB + swz) = v0;
        *(s16x8*)((char*)ys + (sp + 32) * ROWB + swz) = v1;
        if (tid < TILE) y2s[tid] = yr;
        if (it + 1 < ITERS) {
            const char* nsrc = (const char*)(cbase + (size_t)(it + 1) * TILE * DF);
            v0 = *(const s16x8*)(nsrc + sp * ROWB + so);
            v1 = *(const s16x8*)(nsrc + (sp + 32) * ROWB + so);
            yr = (tid < TILE) ? cnb[(it + 1) * TILE + tid] : 0.f;
        }
        __syncthreads();

        #pragma unroll
        for (int ct = 0; ct < 4; ++ct) {
            int pt = ct * 16 + c;
            f32x4 acc = {0.f, 0.f, 0.f, 0.f};
            #pragma unroll
            for (int kp = 0; kp < 2; ++kp) {
                int o = (h * 16 + kp * 64) ^ ((pt & 7) << 4);
                s16x8 bfrag = *(const s16x8*)((const char*)ys + pt * ROWB + o);
                acc = __builtin_amdgcn_mfma_f32_16x16x32_bf16(afrag[kp], bfrag, acc, 0, 0, 0);
            }
            float y2c = y2s[pt];
            float uv[4];
            int q = 0;
            #pragma unroll
            for (int r = 0; r < 4; ++r) {
                uv[r] = fmaf(-0.5f, y2c, acc[r]);
                q |= (uv[r] > gthr[r]) ? 1 : 0;
            }
            if (q) {   // rare: some element within MARGIN of this patch's min
                #pragma unroll
                for (int r = 0; r < 4; ++r) {
                    float d2 = fmaf(-2.f, uv[r], x2r[r]);
                    float d = sqrtf(fmaxf(d2, 0.f));
                    float e = __expf(INV_T * (mval[r] - d));  // underflows to 0 if far
                    ssum[r] += e;
                    tsum[r] = fmaf(e, d, tsum[r]);
                }
            }
        }
    }

    // reduce sums across 16 col-lanes; write partial state
    #pragma unroll
    for (int r = 0; r < 4; ++r) {
        #pragma unroll
        for (int m = 1; m < 16; m <<= 1) {
            ssum[r] += __shfl_xor(ssum[r], m, 16);
            tsum[r] += __shfl_xor(tsum[r], m, 16);
        }
    }
    if (c == 0) {
        int dirb = dir * 4 + b;
        #pragma unroll
        for (int r = 0; r < 4; ++r) {
            int row = row0 + wr * 16 + 4 * h + r;
            float* pp = part + (((size_t)(dirb * MC + cs)) * NPTS + row) * 4;
            pp[0] = mval[r]; pp[1] = ssum[r]; pp[2] = tsum[r];
        }
    }
}

// Merge MC partial states per row, cube, reduce, atomicAdd into out[0].
__global__ __launch_bounds__(256) void merge_kernel(const float* __restrict__ part,
                                                    float* __restrict__ out) {
    __shared__ float red[4];
    int g = blockIdx.x * 256 + threadIdx.x;   // (dir*4+b)*4096 + row
    int dirb = g >> 12;
    int row  = g & 4095;
    const float* p0 = part + (((size_t)dirb * MC) * NPTS + row) * 4;
    float mnv[MC], sv[MC], tv[MC];
    float nm = INFINITY;
    #pragma unroll
    for (int k = 0; k < MC; ++k) {
        const float* p = p0 + (size_t)k * NPTS * 4;
        mnv[k] = p[0]; sv[k] = p[1]; tv[k] = p[2];
        nm = fminf(nm, mnv[k]);
    }
    float S = 0.f, T = 0.f;
    #pragma unroll
    for (int k = 0; k < MC; ++k) {
        float cw = __expf(INV_T * (nm - mnv[k]));
        S += sv[k] * cw;
        T += tv[k] * cw;
    }
    float sm = T / S;
    float v = sm * sm * sm * SCALE;
    #pragma unroll
    for (int m = 1; m < 64; m <<= 1) v += __shfl_xor(v, m, 64);
    if ((threadIdx.x & 63) == 0) red[threadIdx.x >> 6] = v;
    __syncthreads();
    if (threadIdx.x == 0) atomicAdd(out, red[0] + red[1] + red[2] + red[3]);
}

__global__ void zero_kernel(float* out) {
    if (threadIdx.x == 0) out[0] = 0.0f;
}

extern "C" void kernel_launch(void* const* d_in, const int* in_sizes, int n_in,
                              void* d_out, int out_size, void* d_ws, size_t ws_size,
                              hipStream_t stream) {
    const float* x = (const float*)d_in[0];
    const float* y = (const float*)d_in[1];
    float* out = (float*)d_out;
    char* ws = (char*)d_ws;

    u16* xb = (u16*)(ws + OFF_XB);
    u16* yb = (u16*)(ws + OFF_YB);
    float* x2 = (float*)(ws + OFF_X2);
    float* y2 = (float*)(ws + OFF_Y2);
    float* part = (float*)(ws + OFF_PART);

    zero_kernel<<<1, 64, 0, stream>>>(out);
    prep_kernel<<<dim3(1024, 2), 256, 0, stream>>>(x, y, xb, yb, x2, y2);
    softmin_fused<<<dim3(NPTS / TILE, 4 * MC, 2), 256, 0, stream>>>(xb, yb, x2, y2, part);
    merge_kernel<<<128, 256, 0, stream>>>(part, out);
}